// Round 15
// baseline (63.998 us; speedup 1.0000x reference)
//
#include <hip/hip_runtime.h>
#include <stdint.h>

// ---------------------------------------------------------------------------
// GraphBasedSkipConnection, MI355X. f32 I/O; bf16 MFMA GEMMs internally.
//   B=2, H=64, W=64, C=512, C2=256, N = 8192 pixels.
// Round 15 = round 14 (measured best, 63.05us) + T5 s_setprio(1/0) around
// the MFMA clusters in both GEMM kernels. Mechanism (catalog T5/m191):
// setprio pays when co-resident waves are at DIFFERENT phases — our mid
// runs 4 different block types per CU (never inter-synced), out has
// staggered prologue phases. r14's launch_bounds(256,4) guarantees the
// 4-blocks/CU diversity that makes the scheduler hint meaningful.
// ---------------------------------------------------------------------------

typedef __attribute__((ext_vector_type(8))) short bf16x8;
typedef __attribute__((ext_vector_type(4))) float f32x4;

#define EPS_BN 1e-3f

__device__ __forceinline__ short f2bf(float f) {
    union { float f; unsigned u; } cv;
    cv.f = f;
    unsigned r = cv.u + 0x7fffu + ((cv.u >> 16) & 1u);
    return (short)(r >> 16);
}
__device__ __forceinline__ float bf2f(short s) {
    union { unsigned u; float f; } cv;
    cv.u = ((unsigned)(unsigned short)s) << 16;
    return cv.f;
}

// ---- P layout (floats) -----------------------------------------------------
// 0 a1, 1 c1, 2 a4, 3 c4
// 8..264    a2[256]     264..520  c2[256]
// 520..776  a3[256]     776..1032 c3[256]
// 1032..1544 a5[512]    1544..2056 c5[512]
// 2056..2060 w_ea[4]    2060..2064 w_er[4]
// ---------------------------------------------------------------------------

__device__ __forceinline__ void pack_one(const float* __restrict__ W, short* __restrict__ out,
                                         int K, int Ncol, int lb, int tid) {
    int i = lb * 256 + tid;
    int lane = i & 63, tile = i >> 6;
    int ktiles = K >> 5;
    int nt = tile / ktiles, kt = tile - nt * ktiles;
    int kbase = (kt << 5) + ((lane >> 4) << 3);
    int col = (nt << 4) + (lane & 15);
    bf16x8 v;
    #pragma unroll
    for (int j = 0; j < 8; ++j) v[j] = f2bf(W[(kbase + j) * Ncol + col]);
    ((bf16x8*)out)[(tile << 6) + lane] = v;
}

// blocks 0..2047: stencil (xb, agg); 2048..2175 pack W_vu; 2176..2303 pack
// W_eu; 2304..2495 pack W_fc; 2496 computes P.
__global__ __launch_bounds__(256) void k_front(
    const float* __restrict__ x,
    const float* w_ea, const float* b_ea,
    const float* g1, const float* b1, const float* m1, const float* v1,
    const float* w_vu, const float* w_eu, const float* w_fc,
    const float* b_vu, const float* g2, const float* b2_, const float* m2, const float* v2,
    const float* b_eu, const float* g3, const float* b3, const float* m3, const float* v3,
    const float* w_er, const float* b_er,
    const float* g4, const float* b4, const float* m4, const float* v4,
    const float* g5, const float* b5, const float* m5, const float* v5,
    short* __restrict__ xb, short* __restrict__ agg,
    short* BpVu, short* BpEu, short* BpFc, float* P)
{
    int blk = blockIdx.x, t = threadIdx.x;
    if (blk >= 2048) {
        int b = blk - 2048;
        if (b < 128)      { pack_one(w_vu, BpVu, 1024, 256, b, t); }
        else if (b < 256) { pack_one(w_eu, BpEu, 1024, 256, b - 128, t); }
        else if (b < 448) { pack_one(w_fc, BpFc,  768, 512, b - 256, t); }
        else {
            for (int u = t; u < 512; u += 256) {
                float a5 = g5[u] * rsqrtf(v5[u] + EPS_BN);
                P[1032 + u] = a5;
                P[1544 + u] = b5[u] - m5[u] * a5;      // w_fc has no bias
            }
            {
                float a2 = g2[t] * rsqrtf(v2[t] + EPS_BN);
                P[8 + t]   = a2;
                P[264 + t] = (b_vu[t] - m2[t]) * a2 + b2_[t];
                float a3 = g3[t] * rsqrtf(v3[t] + EPS_BN);
                P[520 + t] = a3;
                P[776 + t] = (b_eu[t] - m3[t]) * a3 + b3[t];
            }
            if (t < 4) {
                P[2056 + t] = w_ea[t];
                P[2060 + t] = w_er[t];
            }
            if (t == 0) {
                float a4 = g4[0] * rsqrtf(v4[0] + EPS_BN);
                P[2] = a4;
                P[3] = (b_er[0] - m4[0]) * a4 + b4[0];
                float a1l = g1[0] * rsqrtf(v1[0] + EPS_BN);
                P[0] = a1l;
                P[1] = (b_ea[0] - m1[0]) * a1l + b1[0];
            }
        }
        return;
    }

    float a1 = g1[0] * rsqrtf(v1[0] + EPS_BN);
    float c1 = (b_ea[0] - m1[0]) * a1 + b1[0];
    float w0 = w_ea[0], w1 = w_ea[1], w2 = w_ea[2], w3 = w_ea[3];

    int idx = blk * 256 + t;                    // N*C/8 threads
    int n = idx >> 6;
    int ci = idx & 63;
    int bh = n >> 6, h = bh & 63, w = n & 63;
    int bhb = bh & ~63;
    int rowU = ((bhb + ((h + 63) & 63)) << 6) + w;
    int rowD = ((bhb + ((h + 1) & 63)) << 6) + w;
    int rowL = (bh << 6) + ((w + 63) & 63);
    int rowR = (bh << 6) + ((w + 1) & 63);

    const f32x4* xv = (const f32x4*)x;
    int c4 = ci << 1;
    f32x4 vc[2], vU[2], vD[2], vL[2], vR[2];
    #pragma unroll
    for (int h2 = 0; h2 < 2; ++h2) {
        vc[h2] = xv[(n    << 7) + c4 + h2];
        vU[h2] = xv[(rowU << 7) + c4 + h2];
        vD[h2] = xv[(rowD << 7) + c4 + h2];
        vL[h2] = xv[(rowL << 7) + c4 + h2];
        vR[h2] = xv[(rowR << 7) + c4 + h2];
    }

    bf16x8 ob, xbv;
    #pragma unroll
    for (int h2 = 0; h2 < 2; ++h2) {
        #pragma unroll
        for (int j = 0; j < 4; ++j) {
            int e = h2 * 4 + j;
            float xc = vc[h2][j];
            float S = w0 * (xc * vU[h2][j]) + w1 * (xc * vD[h2][j])
                    + w2 * (xc * vL[h2][j]) + w3 * (xc * vR[h2][j]);
            ob[e]  = f2bf(fmaxf(fmaf(a1, S, c1), 0.f));
            xbv[e] = f2bf(xc);
        }
    }
    int o = (n << 6) + ci;
    ((bf16x8*)agg)[o] = ob;
    ((bf16x8*)xb)[o] = xbv;
}

// Unified middle GEMMs, type = blockIdx>>8 (one block of each type per CU):
//   type 0: uv  = relu(bn2([xb,agg] @ W_vu))          K=1024
//   type 1: Tv  = xb @ Weu_top                        K=512
//   type 2: TeD = (xb .* xb[h+1]) @ Weu_bot           K=512 (product on the fly)
//   type 3: TeR = (xb .* xb[w+1]) @ Weu_bot           K=512
// block: 32 rows x 256 cols, 4 waves (wave 32x64), prefetch-2, grid 1024.
#define MID_LOAD(ga, na_, kc) do {                                            \
    const short* _S; int _off;                                                \
    if (type == 0) { _S = ((kc) < 8) ? xb : agg; _off = ((kc) & 7) << 6; }    \
    else           { _S = xb; _off = (kc) << 6; }                             \
    ga = *(const bf16x8*)(_S + sAoff + _off + lcs);                           \
    if (type >= 2) na_ = *(const bf16x8*)(xb + nAoff + _off + lcs);           \
} while (0)

#define MID_WRITE(slot, ga, na_) do {                                         \
    bf16x8 _va = ga;                                                          \
    if (type >= 2) {                                                          \
        _Pragma("unroll") for (int _j = 0; _j < 8; ++_j)                      \
            _va[_j] = f2bf(bf2f(_va[_j]) * bf2f(na_[_j]));                    \
    }                                                                         \
    ((bf16x8*)sA[slot])[t] = _va;                                             \
} while (0)

#define MID_COMPUTE(slot, kc) do {                                            \
    const short* _Lb = sA[slot];                                              \
    __builtin_amdgcn_s_setprio(1);                                            \
    _Pragma("unroll") for (int _kt = 0; _kt < 2; ++_kt) {                     \
        bf16x8 _af[2];                                                        \
        _Pragma("unroll") for (int _mi = 0; _mi < 2; ++_mi) {                 \
            int _row = (_mi << 4) + (l & 15);                                 \
            int _lcolb = (_kt << 6) + ((l >> 4) << 4);                        \
            int _addr = (_row << 6) + ((_lcolb ^ ((_row & 7) << 4)) >> 1);    \
            _af[_mi] = *(const bf16x8*)(_Lb + _addr);                         \
        }                                                                     \
        int _kt32 = ktbase + ((kc) << 1) + _kt;                               \
        _Pragma("unroll") for (int _nf = 0; _nf < 4; ++_nf) {                 \
            bf16x8 _b = Bp[((((w << 2) + _nf) << 5) + _kt32) * 64 + l];       \
            _Pragma("unroll") for (int _mi = 0; _mi < 2; ++_mi)               \
                acc[_mi][_nf] = __builtin_amdgcn_mfma_f32_16x16x32_bf16(      \
                    _af[_mi], _b, acc[_mi][_nf], 0, 0, 0);                    \
        }                                                                     \
    }                                                                         \
    __builtin_amdgcn_s_setprio(0);                                            \
} while (0)

__global__ __launch_bounds__(256, 4) void k_gemm_mid(
    const short* __restrict__ xb, const short* __restrict__ agg,
    const short* __restrict__ BpVu, const short* __restrict__ BpEu,
    const float* __restrict__ P,
    short* __restrict__ uvb, short* __restrict__ tvb,
    short* __restrict__ teDb, short* __restrict__ teRb)
{
    __shared__ __align__(16) short sA[2][32 * 64];    // 8 KB
    int t = threadIdx.x, l = t & 63, w = t >> 6;
    int type = blockIdx.x >> 8, rs = blockIdx.x & 255;
    int r0 = rs << 5;
    int dr = t >> 3, p8 = t & 7;
    int lcs = (p8 ^ (dr & 7)) << 3;

    int rA = r0 + dr;
    int nA = rA;
    if (type == 2) {                              // roll down (h+1)
        int bh = rA >> 6;
        nA = (((bh & ~63) + (((bh & 63) + 1) & 63)) << 6) + (rA & 63);
    } else if (type == 3) {                       // roll right (w+1)
        nA = (rA & ~63) + ((rA + 1) & 63);
    }
    int sAoff = rA << 9, nAoff = nA << 9;

    int nchunk = (type == 0) ? 16 : 8;
    const bf16x8* Bp = (type == 0) ? (const bf16x8*)BpVu : (const bf16x8*)BpEu;
    int ktbase = (type >= 2) ? 16 : 0;
    short* Out = (type == 0) ? uvb : (type == 1) ? tvb : (type == 2) ? teDb : teRb;

    f32x4 acc[2][4];
    #pragma unroll
    for (int mi = 0; mi < 2; ++mi)
        #pragma unroll
        for (int nf = 0; nf < 4; ++nf) acc[mi][nf] = (f32x4){0.f, 0.f, 0.f, 0.f};

    bf16x8 gA, nAv, gB, nBv;
    MID_LOAD(gA, nAv, 0);
    MID_LOAD(gB, nBv, 1);

    for (int kc2 = 0; kc2 < nchunk; kc2 += 2) {
        MID_WRITE(0, gA, nAv);
        __syncthreads();
        if (kc2 + 2 < nchunk) MID_LOAD(gA, nAv, kc2 + 2);
        MID_COMPUTE(0, kc2);
        MID_WRITE(1, gB, nBv);
        __syncthreads();
        if (kc2 + 3 < nchunk) MID_LOAD(gB, nBv, kc2 + 3);
        MID_COMPUTE(1, kc2 + 1);
    }

    #pragma unroll
    for (int nf = 0; nf < 4; ++nf) {
        int col = (w << 6) + (nf << 4) + (l & 15);
        float aa = P[8 + col], cc = P[264 + col];
        #pragma unroll
        for (int mi = 0; mi < 2; ++mi) {
            int rbase = r0 + (mi << 4) + ((l >> 4) << 2);
            #pragma unroll
            for (int j = 0; j < 4; ++j) {
                float v = acc[mi][nf][j];
                if (type == 0) v = fmaxf(fmaf(v, aa, cc), 0.f);
                Out[(rbase + j) * 256 + col] = f2bf(v);
            }
        }
    }
}

// out = relu(bn5([xb, upd] @ W_fc)), upd computed in-kernel into LDS.
// block: 32 rows x 128 cols (quarter cq), 4 waves (wave 32x32), prefetch-2,
// grid = 256 rowsets x 4 = 1024.
#define OUT_COMPUTE(Lb, kc) do {                                              \
    __builtin_amdgcn_s_setprio(1);                                            \
    _Pragma("unroll") for (int _kt = 0; _kt < 2; ++_kt) {                     \
        bf16x8 _af[2];                                                        \
        _Pragma("unroll") for (int _mi = 0; _mi < 2; ++_mi) {                 \
            int _row = (_mi << 4) + (l & 15);                                 \
            int _lcolb = (_kt << 6) + ((l >> 4) << 4);                        \
            int _addr = (_row << 6) + ((_lcolb ^ ((_row & 7) << 4)) >> 1);    \
            _af[_mi] = *(const bf16x8*)((Lb) + _addr);                        \
        }                                                                     \
        _Pragma("unroll") for (int _nf = 0; _nf < 2; ++_nf) {                 \
            int _nt = (cq << 3) + (w << 1) + _nf;                             \
            bf16x8 _b = Bp[(_nt * 24 + ((kc) << 1) + _kt) * 64 + l];          \
            _Pragma("unroll") for (int _mi = 0; _mi < 2; ++_mi)               \
                acc[_mi][_nf] = __builtin_amdgcn_mfma_f32_16x16x32_bf16(      \
                    _af[_mi], _b, acc[_mi][_nf], 0, 0, 0);                    \
        }                                                                     \
    }                                                                         \
    __builtin_amdgcn_s_setprio(0);                                            \
} while (0)

__global__ __launch_bounds__(256, 4) void k_gemm_out(
    const short* __restrict__ xb,
    const short* __restrict__ tv, const short* __restrict__ teD,
    const short* __restrict__ teR, const short* __restrict__ uv,
    const short* __restrict__ BpFc, const float* __restrict__ P,
    float* __restrict__ out)
{
    __shared__ __align__(16) short sXb[2][32 * 64];   // 8 KB
    __shared__ __align__(16) short updL[4][32 * 64];  // 16 KB
    int t = threadIdx.x, l = t & 63, w = t >> 6;
    int cq = blockIdx.x & 3, rs = blockIdx.x >> 2;
    int r0 = rs << 5;
    const bf16x8* Bp = (const bf16x8*)BpFc;

    int dr = t >> 3, p8 = t & 7;
    int lcs = (p8 ^ (dr & 7)) << 3;
    int xrow = (r0 + dr) << 9;

    // prefetch first two xb chunks before the upd prologue
    bf16x8 gA = *(const bf16x8*)(xb + xrow + lcs);
    bf16x8 gB = *(const bf16x8*)(xb + xrow + 64 + lcs);

    // ---- prologue: upd for rows r0..r0+31, all 256 channels, into LDS ----
    {
        int n = r0 + dr;
        int bh = n >> 6, h = bh & 63, ww = n & 63;
        int bhb = bh & ~63;
        int nUp = ((bhb + ((h + 63) & 63)) << 6) + ww;
        int nLf = (bh << 6) + ((ww + 63) & 63);
        float w0 = P[2060], w1 = P[2061], w2 = P[2062], w3 = P[2063];
        float a4 = P[2], c4 = P[3];
        #pragma unroll
        for (int q = 0; q < 4; ++q) {
            int lc = (q << 6) + lcs;
            bf16x8 vTv = *(const bf16x8*)(tv  + n   * 256 + lc);
            bf16x8 vD  = *(const bf16x8*)(teD + n   * 256 + lc);
            bf16x8 vDu = *(const bf16x8*)(teD + nUp * 256 + lc);
            bf16x8 vR  = *(const bf16x8*)(teR + n   * 256 + lc);
            bf16x8 vRl = *(const bf16x8*)(teR + nLf * 256 + lc);
            bf16x8 vUv = *(const bf16x8*)(uv  + n   * 256 + lc);
            f32x4 a3a = *(const f32x4*)&P[520 + lc], a3b = *(const f32x4*)&P[524 + lc];
            f32x4 c3a = *(const f32x4*)&P[776 + lc], c3b = *(const f32x4*)&P[780 + lc];
            bf16x8 o;
            #pragma unroll
            for (int j = 0; j < 8; ++j) {
                float a3 = (j < 4) ? a3a[j & 3] : a3b[j & 3];
                float c3 = (j < 4) ? c3a[j & 3] : c3b[j & 3];
                float tvv = bf2f(vTv[j]);
                float ueU = fmaxf(fmaf(a3, tvv + bf2f(vDu[j]), c3), 0.f);
                float ueD = fmaxf(fmaf(a3, tvv + bf2f(vD[j]),  c3), 0.f);
                float ueL = fmaxf(fmaf(a3, tvv + bf2f(vRl[j]), c3), 0.f);
                float ueR = fmaxf(fmaf(a3, tvv + bf2f(vR[j]),  c3), 0.f);
                float s = w0 * ueU + w1 * ueD + w2 * ueL + w3 * ueR;
                float ur = fmaxf(fmaf(a4, s, c4), 0.f);
                o[j] = f2bf(ur * bf2f(vUv[j]));
            }
            *(bf16x8*)&updL[q][(dr << 6) + (p8 << 3)] = o;   // swizzled store
        }
    }

    f32x4 acc[2][2];
    #pragma unroll
    for (int mi = 0; mi < 2; ++mi)
        #pragma unroll
        for (int nf = 0; nf < 2; ++nf) acc[mi][nf] = (f32x4){0.f, 0.f, 0.f, 0.f};

    for (int kc2 = 0; kc2 < 8; kc2 += 2) {
        ((bf16x8*)sXb[0])[t] = gA;
        __syncthreads();
        if (kc2 + 2 < 8) gA = *(const bf16x8*)(xb + xrow + ((kc2 + 2) << 6) + lcs);
        OUT_COMPUTE(sXb[0], kc2);
        ((bf16x8*)sXb[1])[t] = gB;
        __syncthreads();
        if (kc2 + 3 < 8) gB = *(const bf16x8*)(xb + xrow + ((kc2 + 3) << 6) + lcs);
        OUT_COMPUTE(sXb[1], kc2 + 1);
    }
    #pragma unroll
    for (int ku = 0; ku < 4; ++ku) OUT_COMPUTE(updL[ku], 8 + ku);

    #pragma unroll
    for (int nf = 0; nf < 2; ++nf) {
        int col = (cq << 7) + (w << 5) + (nf << 4) + (l & 15);
        float a5 = P[1032 + col], c5 = P[1544 + col];
        #pragma unroll
        for (int mi = 0; mi < 2; ++mi) {
            int rbase = r0 + (mi << 4) + ((l >> 4) << 2);
            #pragma unroll
            for (int j = 0; j < 4; ++j) {
                out[(rbase + j) * 512 + col] = fmaxf(fmaf(acc[mi][nf][j], a5, c5), 0.f);
            }
        }
    }
}

extern "C" void kernel_launch(void* const* d_in, const int* in_sizes, int n_in,
                              void* d_out, int out_size, void* d_ws, size_t ws_size,
                              hipStream_t stream)
{
    const float* x    = (const float*)d_in[0];
    const float* w_ea = (const float*)d_in[1];
    const float* b_ea = (const float*)d_in[2];
    const float* g1   = (const float*)d_in[3];
    const float* b1   = (const float*)d_in[4];
    const float* m1   = (const float*)d_in[5];
    const float* v1   = (const float*)d_in[6];
    const float* w_vu = (const float*)d_in[7];
    const float* b_vu = (const float*)d_in[8];
    const float* g2   = (const float*)d_in[9];
    const float* b2   = (const float*)d_in[10];
    const float* m2   = (const float*)d_in[11];
    const float* v2   = (const float*)d_in[12];
    const float* w_eu = (const float*)d_in[13];
    const float* b_eu = (const float*)d_in[14];
    const float* g3   = (const float*)d_in[15];
    const float* b3   = (const float*)d_in[16];
    const float* m3   = (const float*)d_in[17];
    const float* v3   = (const float*)d_in[18];
    const float* w_er = (const float*)d_in[19];
    const float* b_er = (const float*)d_in[20];
    const float* g4   = (const float*)d_in[21];
    const float* b4   = (const float*)d_in[22];
    const float* m4   = (const float*)d_in[23];
    const float* v4   = (const float*)d_in[24];
    const float* w_fc = (const float*)d_in[25];
    const float* g5   = (const float*)d_in[26];
    const float* b5   = (const float*)d_in[27];
    const float* m5   = (const float*)d_in[28];
    const float* v5   = (const float*)d_in[29];

    char* ws = (char*)d_ws;
    float* P = (float*)ws;
    size_t off = 16384;
    short* BpVu = (short*)(ws + off); off += (size_t)1024 * 256 * 2;
    short* BpEu = (short*)(ws + off); off += (size_t)1024 * 256 * 2;
    short* BpFc = (short*)(ws + off); off += (size_t)768 * 512 * 2;
    short* xbb  = (short*)(ws + off); off += (size_t)8192 * 512 * 2;
    short* aggb = (short*)(ws + off); off += (size_t)8192 * 512 * 2;
    short* uvb  = (short*)(ws + off); off += (size_t)8192 * 256 * 2;
    short* tvb  = (short*)(ws + off); off += (size_t)8192 * 256 * 2;
    short* teDb = (short*)(ws + off); off += (size_t)8192 * 256 * 2;
    short* teRb = (short*)(ws + off); off += (size_t)8192 * 256 * 2;

    k_front<<<2497, 256, 0, stream>>>(x, w_ea, b_ea, g1, b1, m1, v1,
                                      w_vu, w_eu, w_fc,
                                      b_vu, g2, b2, m2, v2,
                                      b_eu, g3, b3, m3, v3,
                                      w_er, b_er, g4, b4, m4, v4,
                                      g5, b5, m5, v5,
                                      xbb, aggb, BpVu, BpEu, BpFc, P);
    k_gemm_mid<<<1024, 256, 0, stream>>>(xbb, aggb, BpVu, BpEu, P,
                                         uvb, tvb, teDb, teRb);
    k_gemm_out<<<1024, 256, 0, stream>>>(xbb, tvb, teDb, teRb, uvb, BpFc, P,
                                         (float*)d_out);
}

// Round 16
// 62.779 us; speedup vs baseline: 1.0194x; 1.0194x over previous
//
#include <hip/hip_runtime.h>
#include <stdint.h>

// ---------------------------------------------------------------------------
// GraphBasedSkipConnection, MI355X. f32 I/O; bf16 MFMA GEMMs internally.
//   B=2, H=64, W=64, C=512, C2=256, N = 8192 pixels.
// FINAL = round 14 (measured best, 63.05us): round-7 structure +
// __launch_bounds__(256,4) on both GEMM kernels (keeps VGPR<=128 -> 4
// blocks/CU; the allocator was at/over the 128 cliff without it).
// Ledger: r8 DMA=67.3, r9 64r=72.8, r10 fused=90.3, r11 B-stationary=76.0,
// r12 barrier-free=84.8, r15 setprio=64.0 — all regressions vs this.
//  - k_front: stencil (bf16 x + folded-BN agg) + weight pack + BN params.
//  - k_gemm_mid: 32rx256c blocks, type=blockIdx>>8 (one type per CU),
//    reg-staged prefetch-2, swizzled LDS A-tiles, edge product on the fly.
//  - k_gemm_out: 32rx128c quarters, upd computed in-prologue into LDS.
// ---------------------------------------------------------------------------

typedef __attribute__((ext_vector_type(8))) short bf16x8;
typedef __attribute__((ext_vector_type(4))) float f32x4;

#define EPS_BN 1e-3f

__device__ __forceinline__ short f2bf(float f) {
    union { float f; unsigned u; } cv;
    cv.f = f;
    unsigned r = cv.u + 0x7fffu + ((cv.u >> 16) & 1u);
    return (short)(r >> 16);
}
__device__ __forceinline__ float bf2f(short s) {
    union { unsigned u; float f; } cv;
    cv.u = ((unsigned)(unsigned short)s) << 16;
    return cv.f;
}

// ---- P layout (floats) -----------------------------------------------------
// 0 a1, 1 c1, 2 a4, 3 c4
// 8..264    a2[256]     264..520  c2[256]
// 520..776  a3[256]     776..1032 c3[256]
// 1032..1544 a5[512]    1544..2056 c5[512]
// 2056..2060 w_ea[4]    2060..2064 w_er[4]
// ---------------------------------------------------------------------------

__device__ __forceinline__ void pack_one(const float* __restrict__ W, short* __restrict__ out,
                                         int K, int Ncol, int lb, int tid) {
    int i = lb * 256 + tid;
    int lane = i & 63, tile = i >> 6;
    int ktiles = K >> 5;
    int nt = tile / ktiles, kt = tile - nt * ktiles;
    int kbase = (kt << 5) + ((lane >> 4) << 3);
    int col = (nt << 4) + (lane & 15);
    bf16x8 v;
    #pragma unroll
    for (int j = 0; j < 8; ++j) v[j] = f2bf(W[(kbase + j) * Ncol + col]);
    ((bf16x8*)out)[(tile << 6) + lane] = v;
}

// blocks 0..2047: stencil (xb, agg); 2048..2175 pack W_vu; 2176..2303 pack
// W_eu; 2304..2495 pack W_fc; 2496 computes P.
__global__ __launch_bounds__(256) void k_front(
    const float* __restrict__ x,
    const float* w_ea, const float* b_ea,
    const float* g1, const float* b1, const float* m1, const float* v1,
    const float* w_vu, const float* w_eu, const float* w_fc,
    const float* b_vu, const float* g2, const float* b2_, const float* m2, const float* v2,
    const float* b_eu, const float* g3, const float* b3, const float* m3, const float* v3,
    const float* w_er, const float* b_er,
    const float* g4, const float* b4, const float* m4, const float* v4,
    const float* g5, const float* b5, const float* m5, const float* v5,
    short* __restrict__ xb, short* __restrict__ agg,
    short* BpVu, short* BpEu, short* BpFc, float* P)
{
    int blk = blockIdx.x, t = threadIdx.x;
    if (blk >= 2048) {
        int b = blk - 2048;
        if (b < 128)      { pack_one(w_vu, BpVu, 1024, 256, b, t); }
        else if (b < 256) { pack_one(w_eu, BpEu, 1024, 256, b - 128, t); }
        else if (b < 448) { pack_one(w_fc, BpFc,  768, 512, b - 256, t); }
        else {
            for (int u = t; u < 512; u += 256) {
                float a5 = g5[u] * rsqrtf(v5[u] + EPS_BN);
                P[1032 + u] = a5;
                P[1544 + u] = b5[u] - m5[u] * a5;      // w_fc has no bias
            }
            {
                float a2 = g2[t] * rsqrtf(v2[t] + EPS_BN);
                P[8 + t]   = a2;
                P[264 + t] = (b_vu[t] - m2[t]) * a2 + b2_[t];
                float a3 = g3[t] * rsqrtf(v3[t] + EPS_BN);
                P[520 + t] = a3;
                P[776 + t] = (b_eu[t] - m3[t]) * a3 + b3[t];
            }
            if (t < 4) {
                P[2056 + t] = w_ea[t];
                P[2060 + t] = w_er[t];
            }
            if (t == 0) {
                float a4 = g4[0] * rsqrtf(v4[0] + EPS_BN);
                P[2] = a4;
                P[3] = (b_er[0] - m4[0]) * a4 + b4[0];
                float a1l = g1[0] * rsqrtf(v1[0] + EPS_BN);
                P[0] = a1l;
                P[1] = (b_ea[0] - m1[0]) * a1l + b1[0];
            }
        }
        return;
    }

    float a1 = g1[0] * rsqrtf(v1[0] + EPS_BN);
    float c1 = (b_ea[0] - m1[0]) * a1 + b1[0];
    float w0 = w_ea[0], w1 = w_ea[1], w2 = w_ea[2], w3 = w_ea[3];

    int idx = blk * 256 + t;                    // N*C/8 threads
    int n = idx >> 6;
    int ci = idx & 63;
    int bh = n >> 6, h = bh & 63, w = n & 63;
    int bhb = bh & ~63;
    int rowU = ((bhb + ((h + 63) & 63)) << 6) + w;
    int rowD = ((bhb + ((h + 1) & 63)) << 6) + w;
    int rowL = (bh << 6) + ((w + 63) & 63);
    int rowR = (bh << 6) + ((w + 1) & 63);

    const f32x4* xv = (const f32x4*)x;
    int c4 = ci << 1;
    f32x4 vc[2], vU[2], vD[2], vL[2], vR[2];
    #pragma unroll
    for (int h2 = 0; h2 < 2; ++h2) {
        vc[h2] = xv[(n    << 7) + c4 + h2];
        vU[h2] = xv[(rowU << 7) + c4 + h2];
        vD[h2] = xv[(rowD << 7) + c4 + h2];
        vL[h2] = xv[(rowL << 7) + c4 + h2];
        vR[h2] = xv[(rowR << 7) + c4 + h2];
    }

    bf16x8 ob, xbv;
    #pragma unroll
    for (int h2 = 0; h2 < 2; ++h2) {
        #pragma unroll
        for (int j = 0; j < 4; ++j) {
            int e = h2 * 4 + j;
            float xc = vc[h2][j];
            float S = w0 * (xc * vU[h2][j]) + w1 * (xc * vD[h2][j])
                    + w2 * (xc * vL[h2][j]) + w3 * (xc * vR[h2][j]);
            ob[e]  = f2bf(fmaxf(fmaf(a1, S, c1), 0.f));
            xbv[e] = f2bf(xc);
        }
    }
    int o = (n << 6) + ci;
    ((bf16x8*)agg)[o] = ob;
    ((bf16x8*)xb)[o] = xbv;
}

// Unified middle GEMMs, type = blockIdx>>8 (one block of each type per CU):
//   type 0: uv  = relu(bn2([xb,agg] @ W_vu))          K=1024
//   type 1: Tv  = xb @ Weu_top                        K=512
//   type 2: TeD = (xb .* xb[h+1]) @ Weu_bot           K=512 (product on the fly)
//   type 3: TeR = (xb .* xb[w+1]) @ Weu_bot           K=512
// block: 32 rows x 256 cols, 4 waves (wave 32x64), prefetch-2, grid 1024.
#define MID_LOAD(ga, na_, kc) do {                                            \
    const short* _S; int _off;                                                \
    if (type == 0) { _S = ((kc) < 8) ? xb : agg; _off = ((kc) & 7) << 6; }    \
    else           { _S = xb; _off = (kc) << 6; }                             \
    ga = *(const bf16x8*)(_S + sAoff + _off + lcs);                           \
    if (type >= 2) na_ = *(const bf16x8*)(xb + nAoff + _off + lcs);           \
} while (0)

#define MID_WRITE(slot, ga, na_) do {                                         \
    bf16x8 _va = ga;                                                          \
    if (type >= 2) {                                                          \
        _Pragma("unroll") for (int _j = 0; _j < 8; ++_j)                      \
            _va[_j] = f2bf(bf2f(_va[_j]) * bf2f(na_[_j]));                    \
    }                                                                         \
    ((bf16x8*)sA[slot])[t] = _va;                                             \
} while (0)

#define MID_COMPUTE(slot, kc) do {                                            \
    const short* _Lb = sA[slot];                                              \
    _Pragma("unroll") for (int _kt = 0; _kt < 2; ++_kt) {                     \
        bf16x8 _af[2];                                                        \
        _Pragma("unroll") for (int _mi = 0; _mi < 2; ++_mi) {                 \
            int _row = (_mi << 4) + (l & 15);                                 \
            int _lcolb = (_kt << 6) + ((l >> 4) << 4);                        \
            int _addr = (_row << 6) + ((_lcolb ^ ((_row & 7) << 4)) >> 1);    \
            _af[_mi] = *(const bf16x8*)(_Lb + _addr);                         \
        }                                                                     \
        int _kt32 = ktbase + ((kc) << 1) + _kt;                               \
        _Pragma("unroll") for (int _nf = 0; _nf < 4; ++_nf) {                 \
            bf16x8 _b = Bp[((((w << 2) + _nf) << 5) + _kt32) * 64 + l];       \
            _Pragma("unroll") for (int _mi = 0; _mi < 2; ++_mi)               \
                acc[_mi][_nf] = __builtin_amdgcn_mfma_f32_16x16x32_bf16(      \
                    _af[_mi], _b, acc[_mi][_nf], 0, 0, 0);                    \
        }                                                                     \
    }                                                                         \
} while (0)

__global__ __launch_bounds__(256, 4) void k_gemm_mid(
    const short* __restrict__ xb, const short* __restrict__ agg,
    const short* __restrict__ BpVu, const short* __restrict__ BpEu,
    const float* __restrict__ P,
    short* __restrict__ uvb, short* __restrict__ tvb,
    short* __restrict__ teDb, short* __restrict__ teRb)
{
    __shared__ __align__(16) short sA[2][32 * 64];    // 8 KB
    int t = threadIdx.x, l = t & 63, w = t >> 6;
    int type = blockIdx.x >> 8, rs = blockIdx.x & 255;
    int r0 = rs << 5;
    int dr = t >> 3, p8 = t & 7;
    int lcs = (p8 ^ (dr & 7)) << 3;

    int rA = r0 + dr;
    int nA = rA;
    if (type == 2) {                              // roll down (h+1)
        int bh = rA >> 6;
        nA = (((bh & ~63) + (((bh & 63) + 1) & 63)) << 6) + (rA & 63);
    } else if (type == 3) {                       // roll right (w+1)
        nA = (rA & ~63) + ((rA + 1) & 63);
    }
    int sAoff = rA << 9, nAoff = nA << 9;

    int nchunk = (type == 0) ? 16 : 8;
    const bf16x8* Bp = (type == 0) ? (const bf16x8*)BpVu : (const bf16x8*)BpEu;
    int ktbase = (type >= 2) ? 16 : 0;
    short* Out = (type == 0) ? uvb : (type == 1) ? tvb : (type == 2) ? teDb : teRb;

    f32x4 acc[2][4];
    #pragma unroll
    for (int mi = 0; mi < 2; ++mi)
        #pragma unroll
        for (int nf = 0; nf < 4; ++nf) acc[mi][nf] = (f32x4){0.f, 0.f, 0.f, 0.f};

    bf16x8 gA, nAv, gB, nBv;
    MID_LOAD(gA, nAv, 0);
    MID_LOAD(gB, nBv, 1);

    for (int kc2 = 0; kc2 < nchunk; kc2 += 2) {
        MID_WRITE(0, gA, nAv);
        __syncthreads();
        if (kc2 + 2 < nchunk) MID_LOAD(gA, nAv, kc2 + 2);
        MID_COMPUTE(0, kc2);
        MID_WRITE(1, gB, nBv);
        __syncthreads();
        if (kc2 + 3 < nchunk) MID_LOAD(gB, nBv, kc2 + 3);
        MID_COMPUTE(1, kc2 + 1);
    }

    #pragma unroll
    for (int nf = 0; nf < 4; ++nf) {
        int col = (w << 6) + (nf << 4) + (l & 15);
        float aa = P[8 + col], cc = P[264 + col];
        #pragma unroll
        for (int mi = 0; mi < 2; ++mi) {
            int rbase = r0 + (mi << 4) + ((l >> 4) << 2);
            #pragma unroll
            for (int j = 0; j < 4; ++j) {
                float v = acc[mi][nf][j];
                if (type == 0) v = fmaxf(fmaf(v, aa, cc), 0.f);
                Out[(rbase + j) * 256 + col] = f2bf(v);
            }
        }
    }
}

// out = relu(bn5([xb, upd] @ W_fc)), upd computed in-kernel into LDS.
// block: 32 rows x 128 cols (quarter cq), 4 waves (wave 32x32), prefetch-2,
// grid = 256 rowsets x 4 = 1024.
#define OUT_COMPUTE(Lb, kc) do {                                              \
    _Pragma("unroll") for (int _kt = 0; _kt < 2; ++_kt) {                     \
        bf16x8 _af[2];                                                        \
        _Pragma("unroll") for (int _mi = 0; _mi < 2; ++_mi) {                 \
            int _row = (_mi << 4) + (l & 15);                                 \
            int _lcolb = (_kt << 6) + ((l >> 4) << 4);                        \
            int _addr = (_row << 6) + ((_lcolb ^ ((_row & 7) << 4)) >> 1);    \
            _af[_mi] = *(const bf16x8*)((Lb) + _addr);                        \
        }                                                                     \
        _Pragma("unroll") for (int _nf = 0; _nf < 2; ++_nf) {                 \
            int _nt = (cq << 3) + (w << 1) + _nf;                             \
            bf16x8 _b = Bp[(_nt * 24 + ((kc) << 1) + _kt) * 64 + l];          \
            _Pragma("unroll") for (int _mi = 0; _mi < 2; ++_mi)               \
                acc[_mi][_nf] = __builtin_amdgcn_mfma_f32_16x16x32_bf16(      \
                    _af[_mi], _b, acc[_mi][_nf], 0, 0, 0);                    \
        }                                                                     \
    }                                                                         \
} while (0)

__global__ __launch_bounds__(256, 4) void k_gemm_out(
    const short* __restrict__ xb,
    const short* __restrict__ tv, const short* __restrict__ teD,
    const short* __restrict__ teR, const short* __restrict__ uv,
    const short* __restrict__ BpFc, const float* __restrict__ P,
    float* __restrict__ out)
{
    __shared__ __align__(16) short sXb[2][32 * 64];   // 8 KB
    __shared__ __align__(16) short updL[4][32 * 64];  // 16 KB
    int t = threadIdx.x, l = t & 63, w = t >> 6;
    int cq = blockIdx.x & 3, rs = blockIdx.x >> 2;
    int r0 = rs << 5;
    const bf16x8* Bp = (const bf16x8*)BpFc;

    int dr = t >> 3, p8 = t & 7;
    int lcs = (p8 ^ (dr & 7)) << 3;
    int xrow = (r0 + dr) << 9;

    // prefetch first two xb chunks before the upd prologue
    bf16x8 gA = *(const bf16x8*)(xb + xrow + lcs);
    bf16x8 gB = *(const bf16x8*)(xb + xrow + 64 + lcs);

    // ---- prologue: upd for rows r0..r0+31, all 256 channels, into LDS ----
    {
        int n = r0 + dr;
        int bh = n >> 6, h = bh & 63, ww = n & 63;
        int bhb = bh & ~63;
        int nUp = ((bhb + ((h + 63) & 63)) << 6) + ww;
        int nLf = (bh << 6) + ((ww + 63) & 63);
        float w0 = P[2060], w1 = P[2061], w2 = P[2062], w3 = P[2063];
        float a4 = P[2], c4 = P[3];
        #pragma unroll
        for (int q = 0; q < 4; ++q) {
            int lc = (q << 6) + lcs;
            bf16x8 vTv = *(const bf16x8*)(tv  + n   * 256 + lc);
            bf16x8 vD  = *(const bf16x8*)(teD + n   * 256 + lc);
            bf16x8 vDu = *(const bf16x8*)(teD + nUp * 256 + lc);
            bf16x8 vR  = *(const bf16x8*)(teR + n   * 256 + lc);
            bf16x8 vRl = *(const bf16x8*)(teR + nLf * 256 + lc);
            bf16x8 vUv = *(const bf16x8*)(uv  + n   * 256 + lc);
            f32x4 a3a = *(const f32x4*)&P[520 + lc], a3b = *(const f32x4*)&P[524 + lc];
            f32x4 c3a = *(const f32x4*)&P[776 + lc], c3b = *(const f32x4*)&P[780 + lc];
            bf16x8 o;
            #pragma unroll
            for (int j = 0; j < 8; ++j) {
                float a3 = (j < 4) ? a3a[j & 3] : a3b[j & 3];
                float c3 = (j < 4) ? c3a[j & 3] : c3b[j & 3];
                float tvv = bf2f(vTv[j]);
                float ueU = fmaxf(fmaf(a3, tvv + bf2f(vDu[j]), c3), 0.f);
                float ueD = fmaxf(fmaf(a3, tvv + bf2f(vD[j]),  c3), 0.f);
                float ueL = fmaxf(fmaf(a3, tvv + bf2f(vRl[j]), c3), 0.f);
                float ueR = fmaxf(fmaf(a3, tvv + bf2f(vR[j]),  c3), 0.f);
                float s = w0 * ueU + w1 * ueD + w2 * ueL + w3 * ueR;
                float ur = fmaxf(fmaf(a4, s, c4), 0.f);
                o[j] = f2bf(ur * bf2f(vUv[j]));
            }
            *(bf16x8*)&updL[q][(dr << 6) + (p8 << 3)] = o;   // swizzled store
        }
    }

    f32x4 acc[2][2];
    #pragma unroll
    for (int mi = 0; mi < 2; ++mi)
        #pragma unroll
        for (int nf = 0; nf < 2; ++nf) acc[mi][nf] = (f32x4){0.f, 0.f, 0.f, 0.f};

    for (int kc2 = 0; kc2 < 8; kc2 += 2) {
        ((bf16x8*)sXb[0])[t] = gA;
        __syncthreads();
        if (kc2 + 2 < 8) gA = *(const bf16x8*)(xb + xrow + ((kc2 + 2) << 6) + lcs);
        OUT_COMPUTE(sXb[0], kc2);
        ((bf16x8*)sXb[1])[t] = gB;
        __syncthreads();
        if (kc2 + 3 < 8) gB = *(const bf16x8*)(xb + xrow + ((kc2 + 3) << 6) + lcs);
        OUT_COMPUTE(sXb[1], kc2 + 1);
    }
    #pragma unroll
    for (int ku = 0; ku < 4; ++ku) OUT_COMPUTE(updL[ku], 8 + ku);

    #pragma unroll
    for (int nf = 0; nf < 2; ++nf) {
        int col = (cq << 7) + (w << 5) + (nf << 4) + (l & 15);
        float a5 = P[1032 + col], c5 = P[1544 + col];
        #pragma unroll
        for (int mi = 0; mi < 2; ++mi) {
            int rbase = r0 + (mi << 4) + ((l >> 4) << 2);
            #pragma unroll
            for (int j = 0; j < 4; ++j) {
                out[(rbase + j) * 512 + col] = fmaxf(fmaf(acc[mi][nf][j], a5, c5), 0.f);
            }
        }
    }
}

extern "C" void kernel_launch(void* const* d_in, const int* in_sizes, int n_in,
                              void* d_out, int out_size, void* d_ws, size_t ws_size,
                              hipStream_t stream)
{
    const float* x    = (const float*)d_in[0];
    const float* w_ea = (const float*)d_in[1];
    const float* b_ea = (const float*)d_in[2];
    const float* g1   = (const float*)d_in[3];
    const float* b1   = (const float*)d_in[4];
    const float* m1   = (const float*)d_in[5];
    const float* v1   = (const float*)d_in[6];
    const float* w_vu = (const float*)d_in[7];
    const float* b_vu = (const float*)d_in[8];
    const float* g2   = (const float*)d_in[9];
    const float* b2   = (const float*)d_in[10];
    const float* m2   = (const float*)d_in[11];
    const float* v2   = (const float*)d_in[12];
    const float* w_eu = (const float*)d_in[13];
    const float* b_eu = (const float*)d_in[14];
    const float* g3   = (const float*)d_in[15];
    const float* b3   = (const float*)d_in[16];
    const float* m3   = (const float*)d_in[17];
    const float* v3   = (const float*)d_in[18];
    const float* w_er = (const float*)d_in[19];
    const float* b_er = (const float*)d_in[20];
    const float* g4   = (const float*)d_in[21];
    const float* b4   = (const float*)d_in[22];
    const float* m4   = (const float*)d_in[23];
    const float* v4   = (const float*)d_in[24];
    const float* w_fc = (const float*)d_in[25];
    const float* g5   = (const float*)d_in[26];
    const float* b5   = (const float*)d_in[27];
    const float* m5   = (const float*)d_in[28];
    const float* v5   = (const float*)d_in[29];

    char* ws = (char*)d_ws;
    float* P = (float*)ws;
    size_t off = 16384;
    short* BpVu = (short*)(ws + off); off += (size_t)1024 * 256 * 2;
    short* BpEu = (short*)(ws + off); off += (size_t)1024 * 256 * 2;
    short* BpFc = (short*)(ws + off); off += (size_t)768 * 512 * 2;
    short* xbb  = (short*)(ws + off); off += (size_t)8192 * 512 * 2;
    short* aggb = (short*)(ws + off); off += (size_t)8192 * 512 * 2;
    short* uvb  = (short*)(ws + off); off += (size_t)8192 * 256 * 2;
    short* tvb  = (short*)(ws + off); off += (size_t)8192 * 256 * 2;
    short* teDb = (short*)(ws + off); off += (size_t)8192 * 256 * 2;
    short* teRb = (short*)(ws + off); off += (size_t)8192 * 256 * 2;

    k_front<<<2497, 256, 0, stream>>>(x, w_ea, b_ea, g1, b1, m1, v1,
                                      w_vu, w_eu, w_fc,
                                      b_vu, g2, b2, m2, v2,
                                      b_eu, g3, b3, m3, v3,
                                      w_er, b_er, g4, b4, m4, v4,
                                      g5, b5, m5, v5,
                                      xbb, aggb, BpVu, BpEu, BpFc, P);
    k_gemm_mid<<<1024, 256, 0, stream>>>(xbb, aggb, BpVu, BpEu, P,
                                         uvb, tvb, teDb, teRb);
    k_gemm_out<<<1024, 256, 0, stream>>>(xbb, tvb, teDb, teRb, uvb, BpFc, P,
                                         (float*)d_out);
}